// Round 1
// baseline (1499.284 us; speedup 1.0000x reference)
//
#include <hip/hip_runtime.h>
#include <stdint.h>
#include <math.h>

#define B_N 65536
#define H_N 768
#define V_N 512
#define D_N 1280
#define E_N 8
#define N1  256
#define N2  128

typedef __attribute__((ext_vector_type(8))) short bf16x8;
typedef __attribute__((ext_vector_type(4))) float f32x4;

__device__ __forceinline__ unsigned short f2bf(float f){
  union{float f;uint32_t u;}v; v.f=f;
  uint32_t r = v.u + 0x7FFFu + ((v.u>>16)&1u);
  return (unsigned short)(r>>16);
}
__device__ __forceinline__ float bf2f(unsigned short s){
  union{uint32_t u; float f;}v; v.u = ((uint32_t)s)<<16; return v.f;
}

// ---------------------------------------------------------------------------
// K0: convert expert weights to bf16 in MFMA-fragment-tiled layout.
// w1b tile t=(e*40+ks)*16+gt holds 16x32 (n x k) fragment: elem = l*8+j with
//   n = gt*16 + (l&15), k = ks*32 + 8*(l>>4) + j   (same k<->slot map as A)
// w2b tile t=(e*8+ks2)*8+ft: f = ft*16+(l&15), k = ks2*32+8*(l>>4)+j
// ---------------------------------------------------------------------------
__global__ void convert_weights(const float* __restrict__ w1,
                                const float* __restrict__ w2,
                                unsigned short* __restrict__ w1b,
                                unsigned short* __restrict__ w2b){
  int i = blockIdx.x*256 + threadIdx.x;
  const int W1E = E_N*D_N*N1; // 2621440
  const int W2E = E_N*N1*N2;  // 262144
  if (i < W1E){
    int tile = i >> 9, r = i & 511;
    int l = r >> 3, j = r & 7;
    int gt = tile & 15, t2 = tile >> 4;
    int ks = t2 % 40, e = t2 / 40;
    int k = ks*32 + 8*(l>>4) + j;
    int n = gt*16 + (l&15);
    w1b[i] = f2bf(w1[((size_t)e*D_N + k)*N1 + n]);
  } else {
    i -= W1E;
    if (i < W2E){
      int tile = i >> 9, r = i & 511;
      int l = r >> 3, j = r & 7;
      int ft = tile & 7, t2 = tile >> 3;
      int ks = t2 & 7, e = t2 >> 3;
      int k = ks*32 + 8*(l>>4) + j;
      int f = ft*16 + (l&15);
      w2b[i] = f2bf(w2[((size_t)e*N1 + k)*N2 + f]);
    }
  }
}

// ---------------------------------------------------------------------------
// K1: fused expert MLP, one (64-row, expert) pair per block. 512 threads.
//   GEMM1: 64x256 (K=1280) bf16 MFMA, A staged fp32->bf16 into LDS (dbuf)
//   GEMM2: 64x128 (K=256)  bf16 MFMA from h1s
//   GEMM3: 64x1   (K=128)  fp32 VALU dot + sigmoid -> eo[row][e]
// ---------------------------------------------------------------------------
__global__ __launch_bounds__(512) void expert_kernel(
    const float* __restrict__ text, const float* __restrict__ video,
    const unsigned short* __restrict__ w1b, const float* __restrict__ b1,
    const unsigned short* __restrict__ w2b, const float* __restrict__ b2,
    const float* __restrict__ w3, const float* __restrict__ b3,
    float* __restrict__ eo)
{
  // h1s: [64][264] bf16 (pad 264 -> 2-way banks on ds_read_b128)
  __shared__ __align__(16) unsigned short h1s[64*264];
  // scr: GEMM1 A double-buffer [2][64][40], later h2s [64][136]
  __shared__ __align__(16) unsigned short scr[8704];

  unsigned short* As  = scr;
  unsigned short* h2s = scr;

  const int tid = threadIdx.x;
  const int e  = blockIdx.x & 7;
  const int rb = blockIdx.x >> 3;
  const int r0 = rb * 64;
  const int w  = tid >> 6;      // wave 0..7
  const int l  = tid & 63;
  const int mw = w & 1;         // row half: rows 32*mw..
  const int nw = w >> 1;        // col quarter: cols 64*nw..

  f32x4 acc[2][4];
#pragma unroll
  for (int a=0;a<2;a++)
#pragma unroll
    for (int b=0;b<4;b++) acc[a][b] = (f32x4){0.f,0.f,0.f,0.f};

  const int srow = tid >> 3;          // 0..63
  const int skq  = (tid & 7) * 4;     // 0..28

  // prologue: A(0), B(0)
  float4 areg = *(const float4*)(text + (size_t)(r0 + srow)*H_N + skq);
  const unsigned short* w1e = w1b + (size_t)e*40*16*512;
  bf16x8 bfc[4];
#pragma unroll
  for (int nt=0;nt<4;nt++)
    bfc[nt] = *(const bf16x8*)(w1e + (size_t)((0*16) + (nw*4+nt))*512 + l*8);

  for (int ks=0; ks<40; ++ks){
    // stage current A tile (fp32 -> bf16)
    {
      unsigned short* dst = As + (ks&1)*2560 + srow*40 + skq;
      ushort4 uv; uv.x=f2bf(areg.x); uv.y=f2bf(areg.y); uv.z=f2bf(areg.z); uv.w=f2bf(areg.w);
      *(ushort4*)dst = uv;
    }
    // prefetch next A tile (global fp32)
    if (ks < 39){
      int kn = (ks+1)*32 + skq;
      const float* src = (kn < H_N) ? (text  + (size_t)(r0+srow)*H_N + kn)
                                    : (video + (size_t)(r0+srow)*V_N + (kn - H_N));
      areg = *(const float4*)src;
    }
    __syncthreads();
    // A fragments from LDS
    bf16x8 af[2];
    const unsigned short* asrc = As + (ks&1)*2560;
#pragma unroll
    for (int mt=0;mt<2;mt++)
      af[mt] = *(const bf16x8*)(asrc + (mw*32 + mt*16 + (l&15))*40 + 8*(l>>4));
    // prefetch next B fragments (L2-resident, coalesced)
    bf16x8 bfn[4];
    if (ks < 39){
#pragma unroll
      for (int nt=0;nt<4;nt++)
        bfn[nt] = *(const bf16x8*)(w1e + (size_t)(((ks+1)*16) + (nw*4+nt))*512 + l*8);
    }
#pragma unroll
    for (int mt=0;mt<2;mt++)
#pragma unroll
      for (int nt=0;nt<4;nt++)
        acc[mt][nt] = __builtin_amdgcn_mfma_f32_16x16x32_bf16(af[mt], bfc[nt], acc[mt][nt], 0,0,0);
    if (ks < 39){
#pragma unroll
      for (int nt=0;nt<4;nt++) bfc[nt] = bfn[nt];
    }
  }

  // epilogue 1: bias + relu -> h1s (bf16)
#pragma unroll
  for (int mt=0;mt<2;mt++){
#pragma unroll
    for (int nt=0;nt<4;nt++){
      int n = nw*64 + nt*16 + (l&15);
      float b1v = b1[e*N1 + n];
#pragma unroll
      for (int i=0;i<4;i++){
        int row = mw*32 + mt*16 + (l>>4)*4 + i;
        float v = acc[mt][nt][i] + b1v;
        v = v > 0.f ? v : 0.f;
        h1s[row*264 + n] = f2bf(v);
      }
    }
  }
  __syncthreads();

  // GEMM2: 64x128, K=256
  f32x4 acc2[2][2];
#pragma unroll
  for (int a=0;a<2;a++)
#pragma unroll
    for (int b=0;b<2;b++) acc2[a][b] = (f32x4){0.f,0.f,0.f,0.f};
  const unsigned short* w2e = w2b + (size_t)e*8*8*512;
  const int fw = w >> 1;  // 0..3 -> f cols 32*fw..
#pragma unroll
  for (int ks2=0; ks2<8; ++ks2){
    bf16x8 af2[2], bf2[2];
#pragma unroll
    for (int mt=0;mt<2;mt++)
      af2[mt] = *(const bf16x8*)(h1s + (mw*32 + mt*16 + (l&15))*264 + ks2*32 + 8*(l>>4));
#pragma unroll
    for (int ft=0;ft<2;ft++)
      bf2[ft] = *(const bf16x8*)(w2e + (size_t)((ks2*8) + (fw*2+ft))*512 + l*8);
#pragma unroll
    for (int mt=0;mt<2;mt++)
#pragma unroll
      for (int ft=0;ft<2;ft++)
        acc2[mt][ft] = __builtin_amdgcn_mfma_f32_16x16x32_bf16(af2[mt], bf2[ft], acc2[mt][ft], 0,0,0);
  }
  // epilogue 2: bias + relu -> h2s bf16 (reuses As region; all As reads done)
#pragma unroll
  for (int mt=0;mt<2;mt++){
#pragma unroll
    for (int ft=0;ft<2;ft++){
      int f = fw*32 + ft*16 + (l&15);
      float b2v = b2[e*N2 + f];
#pragma unroll
      for (int i=0;i<4;i++){
        int row = mw*32 + mt*16 + (l>>4)*4 + i;
        float v = acc2[mt][ft][i] + b2v;
        v = v > 0.f ? v : 0.f;
        h2s[row*136 + f] = f2bf(v);
      }
    }
  }
  __syncthreads();

  // GEMM3: eo[row] = sigmoid(h2 . w3 + b3); 8 threads per row
  {
    int r = tid >> 3, j = tid & 7;
    float sum = 0.f;
    const float* w3e = w3 + e*N2;
#pragma unroll
    for (int q=0;q<16;q++){
      int f = j*16 + q;
      sum += bf2f(h2s[r*136 + f]) * w3e[f];
    }
    sum += __shfl_xor(sum, 1);
    sum += __shfl_xor(sum, 2);
    sum += __shfl_xor(sum, 4);
    if (j == 0){
      float x = sum + b3[e];
      eo[(size_t)(r0 + r)*E_N + e] = 1.f/(1.f + expf(-x));
    }
  }
}

// ---------------------------------------------------------------------------
// K2: fp32 routers (chunked-f64 accumulation) + top-2 + softmax + aggregate.
// 32 rows per block, 256 threads. Thread (tr=tid>>5, tc=tid&31) owns
// rows tr*4+i (i<4), cols tc+32*j (j<8).
// ---------------------------------------------------------------------------
__global__ __launch_bounds__(256) void router_kernel(
    const float* __restrict__ text, const float* __restrict__ video,
    const float* __restrict__ tw1, const float* __restrict__ tb1,
    const float* __restrict__ tw2, const float* __restrict__ tb2,
    const float* __restrict__ vw1, const float* __restrict__ vb1,
    const float* __restrict__ vw2, const float* __restrict__ vb2,
    const float* __restrict__ eo, float* __restrict__ out)
{
  __shared__ __align__(16) float Xs[32*36];    // [k][row] padded
  __shared__ __align__(16) float Ws[32*256];   // [k][n]
  __shared__ __align__(16) float W2s[256*8];   // [n][e]

  const int tid = threadIdx.x;
  const int r0  = blockIdx.x * 32;
  const int tr  = tid >> 5;    // 0..7
  const int tc  = tid & 31;

  for (int rt = 0; rt < 2; ++rt){
    const float* X  = rt ? video : text;
    const float* W1 = rt ? vw1 : tw1;
    const float* b1 = rt ? vb1 : tb1;
    const float* W2 = rt ? vw2 : tw2;
    const float* b2 = rt ? vb2 : tb2;
    const int K  = rt ? V_N : H_N;
    const int NK = K / 32;

    __syncthreads();
    for (int i = tid; i < 256*8; i += 256) W2s[i] = W2[i];

    double acc[4][8];
#pragma unroll
    for (int i=0;i<4;i++)
#pragma unroll
      for (int j=0;j<8;j++) acc[i][j] = 0.0;

    for (int kb = 0; kb < NK; ++kb){
      __syncthreads();
      {
        int row = tid >> 3;           // 0..31
        int kq  = (tid & 7) * 4;      // 0..28
        float4 xv = *(const float4*)(X + (size_t)(r0+row)*K + kb*32 + kq);
        Xs[(kq+0)*36 + row] = xv.x;
        Xs[(kq+1)*36 + row] = xv.y;
        Xs[(kq+2)*36 + row] = xv.z;
        Xs[(kq+3)*36 + row] = xv.w;
      }
#pragma unroll
      for (int p = 0; p < 8; ++p){
        int i4 = p*256 + tid;
        int kk = i4 >> 6;
        int n4 = (i4 & 63) * 4;
        *(float4*)(Ws + kk*256 + n4) = *(const float4*)(W1 + (size_t)(kb*32+kk)*N1 + n4);
      }
      __syncthreads();

      float facc[4][8];
#pragma unroll
      for (int i=0;i<4;i++)
#pragma unroll
        for (int j=0;j<8;j++) facc[i][j] = 0.f;

      for (int k = 0; k < 32; ++k){
        float a[4];
        *(float4*)a = *(const float4*)(Xs + k*36 + tr*4);
        float bv[8];
#pragma unroll
        for (int j=0;j<8;j++) bv[j] = Ws[k*256 + tc + 32*j];
#pragma unroll
        for (int i=0;i<4;i++)
#pragma unroll
          for (int j=0;j<8;j++) facc[i][j] += a[i]*bv[j];
      }
#pragma unroll
      for (int i=0;i<4;i++)
#pragma unroll
        for (int j=0;j<8;j++) acc[i][j] += (double)facc[i][j];
    }

    // bias + relu (f32 h is plenty accurate; layer-2 accum in f64)
    float h[4][8];
#pragma unroll
    for (int i=0;i<4;i++)
#pragma unroll
      for (int j=0;j<8;j++){
        double v = acc[i][j] + (double)b1[tc + 32*j];
        h[i][j] = v > 0.0 ? (float)v : 0.f;
      }

    double part[4][8];
#pragma unroll
    for (int i=0;i<4;i++)
#pragma unroll
      for (int e2=0;e2<8;e2++) part[i][e2] = 0.0;
#pragma unroll
    for (int j=0;j<8;j++){
      int n = tc + 32*j;
#pragma unroll
      for (int e2=0;e2<8;e2++){
        double w2v = (double)W2s[n*8 + e2];
#pragma unroll
        for (int i=0;i<4;i++) part[i][e2] += (double)h[i][j] * w2v;
      }
    }
    // reduce over the 32 tc lanes (stays within each 32-lane half of a wave64)
#pragma unroll
    for (int m = 1; m <= 16; m <<= 1){
#pragma unroll
      for (int i=0;i<4;i++)
#pragma unroll
        for (int e2=0;e2<8;e2++) part[i][e2] += __shfl_xor(part[i][e2], m, 64);
    }

    if (tc == 0){
#pragma unroll
      for (int i=0;i<4;i++){
        int row = r0 + tr*4 + i;
        double L[8];
#pragma unroll
        for (int e2=0;e2<8;e2++) L[e2] = part[i][e2] + (double)b2[e2];
        // stable top-2 (ties -> lower index), matching jax.lax.top_k
        int i0 = 0; double v0 = L[0];
#pragma unroll
        for (int e2=1;e2<8;e2++) if (L[e2] > v0){ v0 = L[e2]; i0 = e2; }
        int i1 = -1; double v1 = -1e300;
#pragma unroll
        for (int e2=0;e2<8;e2++) if (e2 != i0 && L[e2] > v1){ v1 = L[e2]; i1 = e2; }
        double e1 = exp(v1 - v0);
        double inv = 1.0/(1.0 + e1);
        float conf = (float)(inv * (double)eo[(size_t)row*E_N + i0]
                           + (e1*inv) * (double)eo[(size_t)row*E_N + i1]);
        out[(size_t)rt*B_N + row] = conf;
      }
    }
  }
}

// ---------------------------------------------------------------------------
extern "C" void kernel_launch(void* const* d_in, const int* in_sizes, int n_in,
                              void* d_out, int out_size, void* d_ws, size_t ws_size,
                              hipStream_t stream){
  const float* text   = (const float*)d_in[0];
  const float* video  = (const float*)d_in[1];
  const float* exp_w1 = (const float*)d_in[2];
  const float* exp_b1 = (const float*)d_in[3];
  const float* exp_w2 = (const float*)d_in[4];
  const float* exp_b2 = (const float*)d_in[5];
  const float* exp_w3 = (const float*)d_in[6];
  const float* exp_b3 = (const float*)d_in[7];
  const float* tw1 = (const float*)d_in[8];
  const float* tb1 = (const float*)d_in[9];
  const float* tw2 = (const float*)d_in[10];
  const float* tb2 = (const float*)d_in[11];
  const float* vw1 = (const float*)d_in[12];
  const float* vb1 = (const float*)d_in[13];
  const float* vw2 = (const float*)d_in[14];
  const float* vb2 = (const float*)d_in[15];
  float* out = (float*)d_out;

  unsigned short* w1b = (unsigned short*)d_ws;                 // 2621440 bf16
  unsigned short* w2b = w1b + (size_t)E_N*D_N*N1;              // 262144 bf16
  float* eo = (float*)(w2b + (size_t)E_N*N1*N2);               // B*E f32

  convert_weights<<<11264, 256, 0, stream>>>(exp_w1, exp_w2, w1b, w2b);
  expert_kernel<<<8192, 512, 0, stream>>>(text, video, w1b, exp_b1, w2b, exp_b2,
                                          exp_w3, exp_b3, eo);
  router_kernel<<<2048, 256, 0, stream>>>(text, video, tw1, tb1, tw2, tb2,
                                          vw1, vb1, vw2, vb2, eo, out);
}

// Round 2
// 893.626 us; speedup vs baseline: 1.6778x; 1.6778x over previous
//
#include <hip/hip_runtime.h>
#include <stdint.h>
#include <math.h>

#define B_N 65536
#define H_N 768
#define V_N 512
#define D_N 1280
#define E_N 8
#define N1  256
#define N2  128

#define W1E (E_N*D_N*N1)   // 2621440
#define W2E (E_N*N1*N2)    // 262144
#define TRE (24*16*512)    // 196608  text router W1 tiles
#define VRE (16*16*512)    // 131072  video router W1 tiles

#define DELTA    5e-3f
#define FLAG_CAP 8192

typedef __attribute__((ext_vector_type(8))) short bf16x8;
typedef __attribute__((ext_vector_type(4))) float f32x4;

__device__ __forceinline__ unsigned short f2bf(float f){
  union{float f;uint32_t u;}v; v.f=f;
  uint32_t r = v.u + 0x7FFFu + ((v.u>>16)&1u);
  return (unsigned short)(r>>16);
}
__device__ __forceinline__ float bf2f(unsigned short s){
  union{uint32_t u; float f;}v; v.u = ((uint32_t)s)<<16; return v.f;
}

// ---------------------------------------------------------------------------
// K0: convert expert weights + router W1 (hi/lo split) to MFMA-fragment tiles.
// Tile t, elem l*8+j: n = (t&15)*16+(l&15), k = (t>>4)*32 + 8*(l>>4) + j.
// Also zeroes the flag counter (runs first in every replay).
// ---------------------------------------------------------------------------
__global__ void convert_weights(const float* __restrict__ w1,
                                const float* __restrict__ w2,
                                const float* __restrict__ tw1,
                                const float* __restrict__ vw1,
                                unsigned short* __restrict__ w1b,
                                unsigned short* __restrict__ w2b,
                                unsigned short* __restrict__ t_hi,
                                unsigned short* __restrict__ t_lo,
                                unsigned short* __restrict__ v_hi,
                                unsigned short* __restrict__ v_lo,
                                int* __restrict__ counter){
  int i = blockIdx.x*256 + threadIdx.x;
  if (i == 0) *counter = 0;
  if (i < W1E){
    int tile = i >> 9, r = i & 511;
    int l = r >> 3, j = r & 7;
    int gt = tile & 15, t2 = tile >> 4;
    int ks = t2 % 40, e = t2 / 40;
    int k = ks*32 + 8*(l>>4) + j;
    int n = gt*16 + (l&15);
    w1b[i] = f2bf(w1[((size_t)e*D_N + k)*N1 + n]);
    return;
  }
  i -= W1E;
  if (i < W2E){
    int tile = i >> 9, r = i & 511;
    int l = r >> 3, j = r & 7;
    int ft = tile & 7, t2 = tile >> 3;
    int ks = t2 & 7, e = t2 >> 3;
    int k = ks*32 + 8*(l>>4) + j;
    int f = ft*16 + (l&15);
    w2b[i] = f2bf(w2[((size_t)e*N1 + k)*N2 + f]);
    return;
  }
  i -= W2E;
  if (i < TRE){
    int tile = i >> 9, r = i & 511;
    int l = r >> 3, j = r & 7;
    int gt = tile & 15, ks = tile >> 4;
    int k = ks*32 + 8*(l>>4) + j;
    int n = gt*16 + (l&15);
    float x = tw1[(size_t)k*N1 + n];
    unsigned short h = f2bf(x);
    t_hi[i] = h;
    t_lo[i] = f2bf(x - bf2f(h));
    return;
  }
  i -= TRE;
  if (i < VRE){
    int tile = i >> 9, r = i & 511;
    int l = r >> 3, j = r & 7;
    int gt = tile & 15, ks = tile >> 4;
    int k = ks*32 + 8*(l>>4) + j;
    int n = gt*16 + (l&15);
    float x = vw1[(size_t)k*N1 + n];
    unsigned short h = f2bf(x);
    v_hi[i] = h;
    v_lo[i] = f2bf(x - bf2f(h));
  }
}

// ---------------------------------------------------------------------------
// K1: fused expert MLP (unchanged from round 1 — verified correct).
// ---------------------------------------------------------------------------
__global__ __launch_bounds__(512) void expert_kernel(
    const float* __restrict__ text, const float* __restrict__ video,
    const unsigned short* __restrict__ w1b, const float* __restrict__ b1,
    const unsigned short* __restrict__ w2b, const float* __restrict__ b2,
    const float* __restrict__ w3, const float* __restrict__ b3,
    float* __restrict__ eo)
{
  __shared__ __align__(16) unsigned short h1s[64*264];
  __shared__ __align__(16) unsigned short scr[8704];

  unsigned short* As  = scr;
  unsigned short* h2s = scr;

  const int tid = threadIdx.x;
  const int e  = blockIdx.x & 7;
  const int rb = blockIdx.x >> 3;
  const int r0 = rb * 64;
  const int w  = tid >> 6;
  const int l  = tid & 63;
  const int mw = w & 1;
  const int nw = w >> 1;

  f32x4 acc[2][4];
#pragma unroll
  for (int a=0;a<2;a++)
#pragma unroll
    for (int b=0;b<4;b++) acc[a][b] = (f32x4){0.f,0.f,0.f,0.f};

  const int srow = tid >> 3;
  const int skq  = (tid & 7) * 4;

  float4 areg = *(const float4*)(text + (size_t)(r0 + srow)*H_N + skq);
  const unsigned short* w1e = w1b + (size_t)e*40*16*512;
  bf16x8 bfc[4];
#pragma unroll
  for (int nt=0;nt<4;nt++)
    bfc[nt] = *(const bf16x8*)(w1e + (size_t)((0*16) + (nw*4+nt))*512 + l*8);

  for (int ks=0; ks<40; ++ks){
    {
      unsigned short* dst = As + (ks&1)*2560 + srow*40 + skq;
      ushort4 uv; uv.x=f2bf(areg.x); uv.y=f2bf(areg.y); uv.z=f2bf(areg.z); uv.w=f2bf(areg.w);
      *(ushort4*)dst = uv;
    }
    if (ks < 39){
      int kn = (ks+1)*32 + skq;
      const float* src = (kn < H_N) ? (text  + (size_t)(r0+srow)*H_N + kn)
                                    : (video + (size_t)(r0+srow)*V_N + (kn - H_N));
      areg = *(const float4*)src;
    }
    __syncthreads();
    bf16x8 af[2];
    const unsigned short* asrc = As + (ks&1)*2560;
#pragma unroll
    for (int mt=0;mt<2;mt++)
      af[mt] = *(const bf16x8*)(asrc + (mw*32 + mt*16 + (l&15))*40 + 8*(l>>4));
    bf16x8 bfn[4];
    if (ks < 39){
#pragma unroll
      for (int nt=0;nt<4;nt++)
        bfn[nt] = *(const bf16x8*)(w1e + (size_t)(((ks+1)*16) + (nw*4+nt))*512 + l*8);
    }
#pragma unroll
    for (int mt=0;mt<2;mt++)
#pragma unroll
      for (int nt=0;nt<4;nt++)
        acc[mt][nt] = __builtin_amdgcn_mfma_f32_16x16x32_bf16(af[mt], bfc[nt], acc[mt][nt], 0,0,0);
    if (ks < 39){
#pragma unroll
      for (int nt=0;nt<4;nt++) bfc[nt] = bfn[nt];
    }
  }

#pragma unroll
  for (int mt=0;mt<2;mt++){
#pragma unroll
    for (int nt=0;nt<4;nt++){
      int n = nw*64 + nt*16 + (l&15);
      float b1v = b1[e*N1 + n];
#pragma unroll
      for (int i=0;i<4;i++){
        int row = mw*32 + mt*16 + (l>>4)*4 + i;
        float v = acc[mt][nt][i] + b1v;
        v = v > 0.f ? v : 0.f;
        h1s[row*264 + n] = f2bf(v);
      }
    }
  }
  __syncthreads();

  f32x4 acc2[2][2];
#pragma unroll
  for (int a=0;a<2;a++)
#pragma unroll
    for (int b=0;b<2;b++) acc2[a][b] = (f32x4){0.f,0.f,0.f,0.f};
  const unsigned short* w2e = w2b + (size_t)e*8*8*512;
  const int fw = w >> 1;
#pragma unroll
  for (int ks2=0; ks2<8; ++ks2){
    bf16x8 af2[2], bf2v[2];
#pragma unroll
    for (int mt=0;mt<2;mt++)
      af2[mt] = *(const bf16x8*)(h1s + (mw*32 + mt*16 + (l&15))*264 + ks2*32 + 8*(l>>4));
#pragma unroll
    for (int ft=0;ft<2;ft++)
      bf2v[ft] = *(const bf16x8*)(w2e + (size_t)((ks2*8) + (fw*2+ft))*512 + l*8);
#pragma unroll
    for (int mt=0;mt<2;mt++)
#pragma unroll
      for (int ft=0;ft<2;ft++)
        acc2[mt][ft] = __builtin_amdgcn_mfma_f32_16x16x32_bf16(af2[mt], bf2v[ft], acc2[mt][ft], 0,0,0);
  }
#pragma unroll
  for (int mt=0;mt<2;mt++){
#pragma unroll
    for (int ft=0;ft<2;ft++){
      int f = fw*32 + ft*16 + (l&15);
      float b2v = b2[e*N2 + f];
#pragma unroll
      for (int i=0;i<4;i++){
        int row = mw*32 + mt*16 + (l>>4)*4 + i;
        float v = acc2[mt][ft][i] + b2v;
        v = v > 0.f ? v : 0.f;
        h2s[row*136 + f] = f2bf(v);
      }
    }
  }
  __syncthreads();

  {
    int r = tid >> 3, j = tid & 7;
    float sum = 0.f;
    const float* w3e = w3 + e*N2;
#pragma unroll
    for (int q=0;q<16;q++){
      int f = j*16 + q;
      sum += bf2f(h2s[r*136 + f]) * w3e[f];
    }
    sum += __shfl_xor(sum, 1);
    sum += __shfl_xor(sum, 2);
    sum += __shfl_xor(sum, 4);
    if (j == 0){
      float x = sum + b3[e];
      eo[(size_t)(r0 + r)*E_N + e] = 1.f/(1.f + expf(-x));
    }
  }
}

// ---------------------------------------------------------------------------
// R1: MFMA router via split-bf16 (hi*hi + hi*lo + lo*hi), fused layer-2,
// top-2 + softmax + aggregation. Flags near-tie rows (gap23 < DELTA) for
// exact f64 recompute in R2. 64 rows x 256 cols per block, 8 waves.
// ---------------------------------------------------------------------------
__global__ __launch_bounds__(512,4) void router_mfma(
    const float* __restrict__ text, const float* __restrict__ video,
    const unsigned short* __restrict__ t_hi, const unsigned short* __restrict__ t_lo,
    const unsigned short* __restrict__ v_hi, const unsigned short* __restrict__ v_lo,
    const float* __restrict__ tb1, const float* __restrict__ tw2, const float* __restrict__ tb2,
    const float* __restrict__ vb1, const float* __restrict__ vw2, const float* __restrict__ vb2,
    const float* __restrict__ eo, float* __restrict__ out,
    int* __restrict__ flags, int* __restrict__ counter)
{
  __shared__ union {
    unsigned short a[4*2560];     // [hi buf0, hi buf1, lo buf0, lo buf1] 64x40 each
    float h[64*264];              // fp32 hidden for layer 2
  } s;
  __shared__ float W2s[256*8];

  const int tid = threadIdx.x;
  const int rt = blockIdx.x >> 10;
  const int r0 = (blockIdx.x & 1023) * 64;
  const float* X = rt ? video : text;
  const unsigned short* Whi = rt ? v_hi : t_hi;
  const unsigned short* Wlo = rt ? v_lo : t_lo;
  const float* b1 = rt ? vb1 : tb1;
  const float* W2 = rt ? vw2 : tw2;
  const float* b2 = rt ? vb2 : tb2;
  const int K  = rt ? V_N : H_N;
  const int NK = K >> 5;

  const int w = tid >> 6, l = tid & 63;
  const int mw = w & 1, nw = w >> 1;
  const int srow = tid >> 3, skq = (tid & 7) * 4;

  for (int i = tid; i < 2048; i += 512) W2s[i] = W2[i];

  f32x4 acc[2][4];
#pragma unroll
  for (int a=0;a<2;a++)
#pragma unroll
    for (int b=0;b<4;b++) acc[a][b] = (f32x4){0.f,0.f,0.f,0.f};

  const float* xrow = X + (size_t)(r0 + srow)*K + skq;
  float4 areg = *(const float4*)xrow;

  for (int ks = 0; ks < NK; ++ks){
    {
      unsigned short* dhi = s.a + (ks&1)*2560 + srow*40 + skq;
      unsigned short* dlo = s.a + (2+(ks&1))*2560 + srow*40 + skq;
      ushort4 uh, ul;
      uh.x = f2bf(areg.x); ul.x = f2bf(areg.x - bf2f(uh.x));
      uh.y = f2bf(areg.y); ul.y = f2bf(areg.y - bf2f(uh.y));
      uh.z = f2bf(areg.z); ul.z = f2bf(areg.z - bf2f(uh.z));
      uh.w = f2bf(areg.w); ul.w = f2bf(areg.w - bf2f(uh.w));
      *(ushort4*)dhi = uh;
      *(ushort4*)dlo = ul;
    }
    if (ks + 1 < NK) areg = *(const float4*)(xrow + (ks+1)*32);
    __syncthreads();

    bf16x8 bh[4], bl[4];
#pragma unroll
    for (int nt=0;nt<4;nt++){
      size_t off = (size_t)(ks*16 + nw*4 + nt)*512 + l*8;
      bh[nt] = *(const bf16x8*)(Whi + off);
      bl[nt] = *(const bf16x8*)(Wlo + off);
    }
    bf16x8 ah[2], al[2];
    const unsigned short* ahi = s.a + (ks&1)*2560;
    const unsigned short* alo = s.a + (2+(ks&1))*2560;
#pragma unroll
    for (int mt=0;mt<2;mt++){
      int ro = (mw*32 + mt*16 + (l&15))*40 + 8*(l>>4);
      ah[mt] = *(const bf16x8*)(ahi + ro);
      al[mt] = *(const bf16x8*)(alo + ro);
    }
#pragma unroll
    for (int mt=0;mt<2;mt++)
#pragma unroll
      for (int nt=0;nt<4;nt++){
        acc[mt][nt] = __builtin_amdgcn_mfma_f32_16x16x32_bf16(ah[mt], bh[nt], acc[mt][nt], 0,0,0);
        acc[mt][nt] = __builtin_amdgcn_mfma_f32_16x16x32_bf16(ah[mt], bl[nt], acc[mt][nt], 0,0,0);
        acc[mt][nt] = __builtin_amdgcn_mfma_f32_16x16x32_bf16(al[mt], bh[nt], acc[mt][nt], 0,0,0);
      }
  }
  __syncthreads();   // done reading s.a; reuse as s.h

  // epilogue 1: h = relu(acc + b1) -> LDS fp32
#pragma unroll
  for (int mt=0;mt<2;mt++){
#pragma unroll
    for (int nt=0;nt<4;nt++){
      int n = nw*64 + nt*16 + (l&15);
      float b1v = b1[n];
#pragma unroll
      for (int i=0;i<4;i++){
        int row = mw*32 + mt*16 + (l>>4)*4 + i;
        float v = acc[mt][nt][i] + b1v;
        s.h[row*264 + n] = v > 0.f ? v : 0.f;
      }
    }
  }
  __syncthreads();

  // layer 2: 8 threads per row, interleaved n = j + 8q (2-way banks max)
  {
    const int r = tid >> 3, j = tid & 7;
    float part[8];
#pragma unroll
    for (int e=0;e<8;e++) part[e] = 0.f;
    for (int q=0;q<32;q++){
      int n = j + 8*q;
      float hv = s.h[r*264 + n];
#pragma unroll
      for (int e=0;e<8;e++) part[e] += hv * W2s[n*8 + e];
    }
#pragma unroll
    for (int m=1;m<=4;m<<=1)
#pragma unroll
      for (int e=0;e<8;e++) part[e] += __shfl_xor(part[e], m);

    if (j == 0){
      int row = r0 + r;
      float L[8];
#pragma unroll
      for (int e=0;e<8;e++) L[e] = part[e] + b2[e];
      int i0 = 0; float v0 = L[0];
#pragma unroll
      for (int e=1;e<8;e++) if (L[e] > v0){ v0 = L[e]; i0 = e; }
      int i1 = -1; float v1 = -1e30f;
#pragma unroll
      for (int e=0;e<8;e++) if (e != i0 && L[e] > v1){ v1 = L[e]; i1 = e; }
      float v2 = -1e30f;
#pragma unroll
      for (int e=0;e<8;e++) if (e != i0 && e != i1 && L[e] > v2) v2 = L[e];
      if (v1 - v2 < DELTA){
        int idx = atomicAdd(counter, 1);
        if (idx < FLAG_CAP) flags[idx] = (rt<<16) | row;
      }
      float e1 = expf(v1 - v0);
      float invd = 1.f/(1.f + e1);
      out[(size_t)rt*B_N + row] = invd*eo[(size_t)row*E_N + i0]
                                + e1*invd*eo[(size_t)row*E_N + i1];
    }
  }
}

// ---------------------------------------------------------------------------
// R2: exact f64 router for flagged near-tie rows. One row per block.
// ---------------------------------------------------------------------------
__global__ __launch_bounds__(256) void router_exact(
    const float* __restrict__ text, const float* __restrict__ video,
    const float* __restrict__ tw1, const float* __restrict__ tb1,
    const float* __restrict__ tw2, const float* __restrict__ tb2,
    const float* __restrict__ vw1, const float* __restrict__ vb1,
    const float* __restrict__ vw2, const float* __restrict__ vb2,
    const float* __restrict__ eo, float* __restrict__ out,
    const int* __restrict__ flags, const int* __restrict__ counter)
{
  int nf = *counter; if (nf > FLAG_CAP) nf = FLAG_CAP;
  if ((int)blockIdx.x >= nf) return;
  int code = flags[blockIdx.x];
  int rt = code >> 16, row = code & 0xFFFF;
  const float* X  = rt ? video : text;
  const float* W1 = rt ? vw1 : tw1;
  const float* b1 = rt ? vb1 : tb1;
  const float* W2 = rt ? vw2 : tw2;
  const float* b2 = rt ? vb2 : tb2;
  const int K = rt ? V_N : H_N;

  __shared__ float xs[H_N];
  __shared__ double red[4][8];
  const int tid = threadIdx.x;
  for (int k = tid; k < K; k += 256) xs[k] = X[(size_t)row*K + k];
  __syncthreads();

  double sAcc = 0.0;
  for (int k = 0; k < K; ++k)
    sAcc += (double)xs[k] * (double)W1[(size_t)k*N1 + tid];
  sAcc += (double)b1[tid];
  double h = sAcc > 0.0 ? sAcc : 0.0;

  double p[8];
#pragma unroll
  for (int e=0;e<8;e++) p[e] = h * (double)W2[tid*8 + e];
#pragma unroll
  for (int m=1;m<=32;m<<=1)
#pragma unroll
    for (int e=0;e<8;e++) p[e] += __shfl_xor(p[e], m);
  if ((tid & 63) == 0){
#pragma unroll
    for (int e=0;e<8;e++) red[tid>>6][e] = p[e];
  }
  __syncthreads();
  if (tid == 0){
    double L[8];
#pragma unroll
    for (int e=0;e<8;e++) L[e] = red[0][e]+red[1][e]+red[2][e]+red[3][e] + (double)b2[e];
    int i0 = 0; double v0 = L[0];
#pragma unroll
    for (int e=1;e<8;e++) if (L[e] > v0){ v0 = L[e]; i0 = e; }
    int i1 = -1; double v1 = -1e300;
#pragma unroll
    for (int e=0;e<8;e++) if (e != i0 && L[e] > v1){ v1 = L[e]; i1 = e; }
    double e1 = exp(v1 - v0);
    double invd = 1.0/(1.0 + e1);
    out[(size_t)rt*B_N + row] = (float)(invd*(double)eo[(size_t)row*E_N + i0]
                                      + e1*invd*(double)eo[(size_t)row*E_N + i1]);
  }
}

// ---------------------------------------------------------------------------
extern "C" void kernel_launch(void* const* d_in, const int* in_sizes, int n_in,
                              void* d_out, int out_size, void* d_ws, size_t ws_size,
                              hipStream_t stream){
  const float* text   = (const float*)d_in[0];
  const float* video  = (const float*)d_in[1];
  const float* exp_w1 = (const float*)d_in[2];
  const float* exp_b1 = (const float*)d_in[3];
  const float* exp_w2 = (const float*)d_in[4];
  const float* exp_b2 = (const float*)d_in[5];
  const float* exp_w3 = (const float*)d_in[6];
  const float* exp_b3 = (const float*)d_in[7];
  const float* tw1 = (const float*)d_in[8];
  const float* tb1 = (const float*)d_in[9];
  const float* tw2 = (const float*)d_in[10];
  const float* tb2 = (const float*)d_in[11];
  const float* vw1 = (const float*)d_in[12];
  const float* vb1 = (const float*)d_in[13];
  const float* vw2 = (const float*)d_in[14];
  const float* vb2 = (const float*)d_in[15];
  float* out = (float*)d_out;

  unsigned short* w1b  = (unsigned short*)d_ws;          // 2621440
  unsigned short* w2b  = w1b  + W1E;                     // 262144
  unsigned short* t_hi = w2b  + W2E;                     // 196608
  unsigned short* t_lo = t_hi + TRE;                     // 196608
  unsigned short* v_hi = t_lo + TRE;                     // 131072
  unsigned short* v_lo = v_hi + VRE;                     // 131072
  float* eo    = (float*)(v_lo + VRE);                   // B*E f32
  int*   counter = (int*)(eo + (size_t)B_N*E_N);
  int*   flags   = counter + 4;                          // FLAG_CAP ints

  convert_weights<<<12544, 256, 0, stream>>>(exp_w1, exp_w2, tw1, vw1,
                                             w1b, w2b, t_hi, t_lo, v_hi, v_lo,
                                             counter);
  expert_kernel<<<8192, 512, 0, stream>>>(text, video, w1b, exp_b1, w2b, exp_b2,
                                          exp_w3, exp_b3, eo);
  router_mfma<<<2048, 512, 0, stream>>>(text, video, t_hi, t_lo, v_hi, v_lo,
                                        tb1, tw2, tb2, vb1, vw2, vb2,
                                        eo, out, flags, counter);
  router_exact<<<FLAG_CAP, 256, 0, stream>>>(text, video, tw1, tb1, tw2, tb2,
                                             vw1, vb1, vw2, vb2,
                                             eo, out, flags, counter);
}

// Round 4
// 635.911 us; speedup vs baseline: 2.3577x; 1.4053x over previous
//
#include <hip/hip_runtime.h>
#include <stdint.h>
#include <math.h>

#define B_N 65536
#define H_N 768
#define V_N 512
#define D_N 1280
#define E_N 8
#define N1  256
#define N2  128

#define W1E (E_N*D_N*N1)   // 2621440
#define W2E (E_N*N1*N2)    // 262144
#define TRE (24*16*512)    // 196608  text router W1 tiles
#define VRE (16*16*512)    // 131072  video router W1 tiles

#define DELTA    5e-3f
#define FLAG_CAP 8192

typedef __attribute__((ext_vector_type(8))) short bf16x8;
typedef __attribute__((ext_vector_type(4))) float f32x4;

__device__ __forceinline__ unsigned short f2bf(float f){
  union{float f;uint32_t u;}v; v.f=f;
  uint32_t r = v.u + 0x7FFFu + ((v.u>>16)&1u);
  return (unsigned short)(r>>16);
}
__device__ __forceinline__ float bf2f(unsigned short s){
  union{uint32_t u; float f;}v; v.u = ((uint32_t)s)<<16; return v.f;
}

// ---------------------------------------------------------------------------
// K0: convert expert weights + router W1 (hi/lo split) to MFMA-fragment tiles.
// Tile t, elem l*8+j: n = (t&15)*16+(l&15), k = (t>>4)*32 + 8*(l>>4) + j.
// Also zeroes flag counter + per-expert bucket counts (runs first each replay).
// ---------------------------------------------------------------------------
__global__ void convert_weights(const float* __restrict__ w1,
                                const float* __restrict__ w2,
                                const float* __restrict__ tw1,
                                const float* __restrict__ vw1,
                                unsigned short* __restrict__ w1b,
                                unsigned short* __restrict__ w2b,
                                unsigned short* __restrict__ t_hi,
                                unsigned short* __restrict__ t_lo,
                                unsigned short* __restrict__ v_hi,
                                unsigned short* __restrict__ v_lo,
                                int* __restrict__ counters){
  int i = blockIdx.x*256 + threadIdx.x;
  if (i < 16) counters[i] = 0;   // [0]=flag count, [8..15]=bucket counts
  if (i < W1E){
    int tile = i >> 9, r = i & 511;
    int l = r >> 3, j = r & 7;
    int gt = tile & 15, t2 = tile >> 4;
    int ks = t2 % 40, e = t2 / 40;
    int k = ks*32 + 8*(l>>4) + j;
    int n = gt*16 + (l&15);
    w1b[i] = f2bf(w1[((size_t)e*D_N + k)*N1 + n]);
    return;
  }
  i -= W1E;
  if (i < W2E){
    int tile = i >> 9, r = i & 511;
    int l = r >> 3, j = r & 7;
    int ft = tile & 7, t2 = tile >> 3;
    int ks = t2 & 7, e = t2 >> 3;
    int k = ks*32 + 8*(l>>4) + j;
    int f = ft*16 + (l&15);
    w2b[i] = f2bf(w2[((size_t)e*N1 + k)*N2 + f]);
    return;
  }
  i -= W2E;
  if (i < TRE){
    int tile = i >> 9, r = i & 511;
    int l = r >> 3, j = r & 7;
    int gt = tile & 15, ks = tile >> 4;
    int k = ks*32 + 8*(l>>4) + j;
    int n = gt*16 + (l&15);
    float x = tw1[(size_t)k*N1 + n];
    unsigned short h = f2bf(x);
    t_hi[i] = h;
    t_lo[i] = f2bf(x - bf2f(h));
    return;
  }
  i -= TRE;
  if (i < VRE){
    int tile = i >> 9, r = i & 511;
    int l = r >> 3, j = r & 7;
    int gt = tile & 15, ks = tile >> 4;
    int k = ks*32 + 8*(l>>4) + j;
    int n = gt*16 + (l&15);
    float x = vw1[(size_t)k*N1 + n];
    unsigned short h = f2bf(x);
    v_hi[i] = h;
    v_lo[i] = f2bf(x - bf2f(h));
  }
}

// ---------------------------------------------------------------------------
// R1: MFMA router via split-bf16 (hi*hi + hi*lo + lo*hi), fused layer-2,
// top-2 + softmax -> selIdx/selW. Flags near-tie rows (gap23 < DELTA).
// 64 rows x 256 cols per block, 8 waves.
// ---------------------------------------------------------------------------
__global__ __launch_bounds__(512,4) void router_mfma(
    const float* __restrict__ text, const float* __restrict__ video,
    const unsigned short* __restrict__ t_hi, const unsigned short* __restrict__ t_lo,
    const unsigned short* __restrict__ v_hi, const unsigned short* __restrict__ v_lo,
    const float* __restrict__ tb1, const float* __restrict__ tw2, const float* __restrict__ tb2,
    const float* __restrict__ vb1, const float* __restrict__ vw2, const float* __restrict__ vb2,
    int* __restrict__ selIdx, float2* __restrict__ selW,
    int* __restrict__ flags, int* __restrict__ counters)
{
  __shared__ union {
    unsigned short a[4*2560];
    float h[64*264];
  } s;
  __shared__ float W2s[256*8];

  const int tid = threadIdx.x;
  const int rt = blockIdx.x >> 10;
  const int r0 = (blockIdx.x & 1023) * 64;
  const float* X = rt ? video : text;
  const unsigned short* Whi = rt ? v_hi : t_hi;
  const unsigned short* Wlo = rt ? v_lo : t_lo;
  const float* b1 = rt ? vb1 : tb1;
  const float* W2 = rt ? vw2 : tw2;
  const float* b2 = rt ? vb2 : tb2;
  const int K  = rt ? V_N : H_N;
  const int NK = K >> 5;

  const int w = tid >> 6, l = tid & 63;
  const int mw = w & 1, nw = w >> 1;
  const int srow = tid >> 3, skq = (tid & 7) * 4;

  for (int i = tid; i < 2048; i += 512) W2s[i] = W2[i];

  f32x4 acc[2][4];
#pragma unroll
  for (int a=0;a<2;a++)
#pragma unroll
    for (int b=0;b<4;b++) acc[a][b] = (f32x4){0.f,0.f,0.f,0.f};

  const float* xrow = X + (size_t)(r0 + srow)*K + skq;
  float4 areg = *(const float4*)xrow;

  for (int ks = 0; ks < NK; ++ks){
    {
      unsigned short* dhi = s.a + (ks&1)*2560 + srow*40 + skq;
      unsigned short* dlo = s.a + (2+(ks&1))*2560 + srow*40 + skq;
      ushort4 uh, ul;
      uh.x = f2bf(areg.x); ul.x = f2bf(areg.x - bf2f(uh.x));
      uh.y = f2bf(areg.y); ul.y = f2bf(areg.y - bf2f(uh.y));
      uh.z = f2bf(areg.z); ul.z = f2bf(areg.z - bf2f(uh.z));
      uh.w = f2bf(areg.w); ul.w = f2bf(areg.w - bf2f(uh.w));
      *(ushort4*)dhi = uh;
      *(ushort4*)dlo = ul;
    }
    if (ks + 1 < NK) areg = *(const float4*)(xrow + (ks+1)*32);
    __syncthreads();

    bf16x8 bh[4], bl[4];
#pragma unroll
    for (int nt=0;nt<4;nt++){
      size_t off = (size_t)(ks*16 + nw*4 + nt)*512 + l*8;
      bh[nt] = *(const bf16x8*)(Whi + off);
      bl[nt] = *(const bf16x8*)(Wlo + off);
    }
    bf16x8 ah[2], al[2];
    const unsigned short* ahi = s.a + (ks&1)*2560;
    const unsigned short* alo = s.a + (2+(ks&1))*2560;
#pragma unroll
    for (int mt=0;mt<2;mt++){
      int ro = (mw*32 + mt*16 + (l&15))*40 + 8*(l>>4);
      ah[mt] = *(const bf16x8*)(ahi + ro);
      al[mt] = *(const bf16x8*)(alo + ro);
    }
#pragma unroll
    for (int mt=0;mt<2;mt++)
#pragma unroll
      for (int nt=0;nt<4;nt++){
        acc[mt][nt] = __builtin_amdgcn_mfma_f32_16x16x32_bf16(ah[mt], bh[nt], acc[mt][nt], 0,0,0);
        acc[mt][nt] = __builtin_amdgcn_mfma_f32_16x16x32_bf16(ah[mt], bl[nt], acc[mt][nt], 0,0,0);
        acc[mt][nt] = __builtin_amdgcn_mfma_f32_16x16x32_bf16(al[mt], bh[nt], acc[mt][nt], 0,0,0);
      }
  }
  __syncthreads();

#pragma unroll
  for (int mt=0;mt<2;mt++){
#pragma unroll
    for (int nt=0;nt<4;nt++){
      int n = nw*64 + nt*16 + (l&15);
      float b1v = b1[n];
#pragma unroll
      for (int i=0;i<4;i++){
        int row = mw*32 + mt*16 + (l>>4)*4 + i;
        float v = acc[mt][nt][i] + b1v;
        s.h[row*264 + n] = v > 0.f ? v : 0.f;
      }
    }
  }
  __syncthreads();

  {
    const int r = tid >> 3, j = tid & 7;
    float part[8];
#pragma unroll
    for (int e=0;e<8;e++) part[e] = 0.f;
    for (int q=0;q<32;q++){
      int n = j + 8*q;
      float hv = s.h[r*264 + n];
#pragma unroll
      for (int e=0;e<8;e++) part[e] += hv * W2s[n*8 + e];
    }
#pragma unroll
    for (int m=1;m<=4;m<<=1)
#pragma unroll
      for (int e=0;e<8;e++) part[e] += __shfl_xor(part[e], m);

    if (j == 0){
      int row = r0 + r;
      float L[8];
#pragma unroll
      for (int e=0;e<8;e++) L[e] = part[e] + b2[e];
      int i0 = 0; float v0 = L[0];
#pragma unroll
      for (int e=1;e<8;e++) if (L[e] > v0){ v0 = L[e]; i0 = e; }
      int i1 = -1; float v1 = -1e30f;
#pragma unroll
      for (int e=0;e<8;e++) if (e != i0 && L[e] > v1){ v1 = L[e]; i1 = e; }
      float v2 = -1e30f;
#pragma unroll
      for (int e=0;e<8;e++) if (e != i0 && e != i1 && L[e] > v2) v2 = L[e];
      if (v1 - v2 < DELTA){
        int idx = atomicAdd(&counters[0], 1);
        if (idx < FLAG_CAP) flags[idx] = (rt<<16) | row;
      }
      float e1 = expf(v1 - v0);
      float invd = 1.f/(1.f + e1);
      selIdx[rt*B_N + row] = i0 | (i1 << 8);
      selW[rt*B_N + row] = make_float2(invd, e1*invd);
    }
  }
}

// ---------------------------------------------------------------------------
// R2: exact f64 router for flagged near-tie rows -> overwrite selIdx/selW.
// ---------------------------------------------------------------------------
__global__ __launch_bounds__(256) void router_exact(
    const float* __restrict__ text, const float* __restrict__ video,
    const float* __restrict__ tw1, const float* __restrict__ tb1,
    const float* __restrict__ tw2, const float* __restrict__ tb2,
    const float* __restrict__ vw1, const float* __restrict__ vb1,
    const float* __restrict__ vw2, const float* __restrict__ vb2,
    int* __restrict__ selIdx, float2* __restrict__ selW,
    const int* __restrict__ flags, const int* __restrict__ counters)
{
  int nf = counters[0]; if (nf > FLAG_CAP) nf = FLAG_CAP;
  if ((int)blockIdx.x >= nf) return;
  int code = flags[blockIdx.x];
  int rt = code >> 16, row = code & 0xFFFF;
  const float* X  = rt ? video : text;
  const float* W1 = rt ? vw1 : tw1;
  const float* b1 = rt ? vb1 : tb1;
  const float* W2 = rt ? vw2 : tw2;
  const float* b2 = rt ? vb2 : tb2;
  const int K = rt ? V_N : H_N;

  __shared__ float xs[H_N];
  __shared__ double red[4][8];
  const int tid = threadIdx.x;
  for (int k = tid; k < K; k += 256) xs[k] = X[(size_t)row*K + k];
  __syncthreads();

  double sAcc = 0.0;
  for (int k = 0; k < K; ++k)
    sAcc += (double)xs[k] * (double)W1[(size_t)k*N1 + tid];
  sAcc += (double)b1[tid];
  double h = sAcc > 0.0 ? sAcc : 0.0;

  double p[8];
#pragma unroll
  for (int e=0;e<8;e++) p[e] = h * (double)W2[tid*8 + e];
#pragma unroll
  for (int m=1;m<=32;m<<=1)
#pragma unroll
    for (int e=0;e<8;e++) p[e] += __shfl_xor(p[e], m);
  if ((tid & 63) == 0){
#pragma unroll
    for (int e=0;e<8;e++) red[tid>>6][e] = p[e];
  }
  __syncthreads();
  if (tid == 0){
    double L[8];
#pragma unroll
    for (int e=0;e<8;e++) L[e] = red[0][e]+red[1][e]+red[2][e]+red[3][e] + (double)b2[e];
    int i0 = 0; double v0 = L[0];
#pragma unroll
    for (int e=1;e<8;e++) if (L[e] > v0){ v0 = L[e]; i0 = e; }
    int i1 = -1; double v1 = -1e300;
#pragma unroll
    for (int e=0;e<8;e++) if (e != i0 && L[e] > v1){ v1 = L[e]; i1 = e; }
    double e1 = exp(v1 - v0);
    double invd = 1.0/(1.0 + e1);
    selIdx[rt*B_N + row] = i0 | (i1 << 8);
    selW[rt*B_N + row] = make_float2((float)invd, (float)(e1*invd));
  }
}

// ---------------------------------------------------------------------------
// BB: build per-expert row buckets from selIdx (block-aggregated atomics).
// ---------------------------------------------------------------------------
__global__ __launch_bounds__(256) void bucket_build(
    const int* __restrict__ selIdx, int* __restrict__ bucket,
    int* __restrict__ counters)
{
  __shared__ int lcnt[8], lbase[8], lpos[8];
  const int tid = threadIdx.x;
  const int row = blockIdx.x*256 + tid;
  if (tid < 8){ lcnt[tid] = 0; lpos[tid] = 0; }
  __syncthreads();
  int st = selIdx[row], sv = selIdx[B_N + row];
  int mask = (1<<(st&7)) | (1<<((st>>8)&7)) | (1<<(sv&7)) | (1<<((sv>>8)&7));
#pragma unroll
  for (int e=0;e<8;e++) if ((mask>>e)&1) atomicAdd(&lcnt[e], 1);
  __syncthreads();
  if (tid < 8) lbase[tid] = atomicAdd(&counters[8+tid], lcnt[tid]);
  __syncthreads();
#pragma unroll
  for (int e=0;e<8;e++)
    if ((mask>>e)&1){
      int p = atomicAdd(&lpos[e], 1);
      bucket[e*B_N + lbase[e] + p] = row;
    }
}

// ---------------------------------------------------------------------------
// K1: sparse expert MLP over bucketed rows. Block = 128 gathered rows x one
// expert, 512 threads, 8 waves (2 row-halves x 4 col-quarters), 64x64 wave
// tiles. A staged f32->bf16 into fragment-linear LDS (conflict-free b128),
// B from global (fragment tiles, L2-resident via e<->XCD swizzle).
// GEMM2 from h1s fragment tiles; GEMM3 in registers (+b2, relu!) + shuffle.
// ---------------------------------------------------------------------------
__global__ __launch_bounds__(512) void expert_sparse(
    const float* __restrict__ text, const float* __restrict__ video,
    const unsigned short* __restrict__ w1b, const float* __restrict__ b1,
    const unsigned short* __restrict__ w2b, const float* __restrict__ b2,
    const float* __restrict__ w3, const float* __restrict__ b3,
    const int* __restrict__ bucket, const int* __restrict__ counters,
    float* __restrict__ eo)
{
  __shared__ __align__(16) unsigned short As[4096];    // 8 KB (one K-chunk, frag tiles)
  __shared__ __align__(16) unsigned short h1s[32768];  // 64 KB (frag tiles for GEMM2)
  __shared__ int rl[128];

  const int tid = threadIdx.x;
  const int e = blockIdx.x & 7;          // expert <-> XCD affinity
  const int t = blockIdx.x >> 3;
  const int n_e = counters[8 + e];
  if (t*128 >= n_e) return;

  if (tid < 128){
    int idx = t*128 + tid;
    rl[tid] = (idx < n_e) ? bucket[e*B_N + idx] : -1;
  }
  __syncthreads();

  const int w = tid >> 6, l = tid & 63;
  const int mw = w & 1, nw = w >> 1;

  const int sridx = rl[(tid>>6)*16 + (l&15)];
  const int srr = sridx < 0 ? 0 : sridx;
  const float* tb = text  + (size_t)srr*H_N + (l>>4)*8;
  const float* vb = video + (size_t)srr*V_N + (l>>4)*8;

  f32x4 acc[4][4];
#pragma unroll
  for (int a=0;a<4;a++)
#pragma unroll
    for (int b=0;b<4;b++) acc[a][b] = (f32x4){0.f,0.f,0.f,0.f};

  const unsigned short* w1e = w1b + (size_t)e*40*16*512;

  float4 fa0 = *(const float4*)tb;        // ks=0 (k<768)
  float4 fa1 = *(const float4*)(tb + 4);
  bf16x8 bfc[4];
#pragma unroll
  for (int nt=0;nt<4;nt++)
    bfc[nt] = *(const bf16x8*)(w1e + (size_t)(nw*4 + nt)*512 + l*8);

  for (int ks = 0; ks < 40; ++ks){
    {
      union { bf16x8 v; unsigned short u[8]; } sw;
      sw.u[0]=f2bf(fa0.x); sw.u[1]=f2bf(fa0.y); sw.u[2]=f2bf(fa0.z); sw.u[3]=f2bf(fa0.w);
      sw.u[4]=f2bf(fa1.x); sw.u[5]=f2bf(fa1.y); sw.u[6]=f2bf(fa1.z); sw.u[7]=f2bf(fa1.w);
      *(bf16x8*)(As + tid*8) = sw.v;
    }
    if (ks < 39){
      int k0 = (ks+1)*32;
      const float* p = (k0 < H_N) ? (tb + k0) : (vb + (k0 - H_N));
      fa0 = *(const float4*)p;
      fa1 = *(const float4*)(p + 4);
    }
    __syncthreads();

    bf16x8 af[4];
#pragma unroll
    for (int mt=0;mt<4;mt++)
      af[mt] = *(const bf16x8*)(As + (mw*4+mt)*512 + l*8);

    bf16x8 bfn[4];
    if (ks < 39){
#pragma unroll
      for (int nt=0;nt<4;nt++)
        bfn[nt] = *(const bf16x8*)(w1e + (size_t)((ks+1)*16 + nw*4 + nt)*512 + l*8);
    }
#pragma unroll
    for (int mt=0;mt<4;mt++)
#pragma unroll
      for (int nt=0;nt<4;nt++)
        acc[mt][nt] = __builtin_amdgcn_mfma_f32_16x16x32_bf16(af[mt], bfc[nt], acc[mt][nt], 0,0,0);
    if (ks < 39){
#pragma unroll
      for (int nt=0;nt<4;nt++) bfc[nt] = bfn[nt];
    }
    __syncthreads();
  }

  // epilogue 1: h1 = relu(acc + b1) -> h1s fragment tiles (GEMM2 A-operand)
#pragma unroll
  for (int mt=0;mt<4;mt++){
#pragma unroll
    for (int nt=0;nt<4;nt++){
      int n = nw*64 + nt*16 + (l&15);
      float b1v = b1[e*N1 + n];
      int tile = (mw*4+mt)*8 + (n>>5);
      int sub  = 16*((n>>3)&3);
      int jj   = n & 7;
#pragma unroll
      for (int i=0;i<4;i++){
        int r15 = (l>>4)*4 + i;
        float v = acc[mt][nt][i] + b1v;
        v = v > 0.f ? v : 0.f;
        h1s[tile*512 + (r15 + sub)*8 + jj] = f2bf(v);
      }
    }
  }
  __syncthreads();

  // GEMM2: 128x128, K=256 from h1s frag tiles; B (w2b tiles) from global.
  f32x4 acc2[4][2];
#pragma unroll
  for (int a=0;a<4;a++)
#pragma unroll
    for (int b=0;b<2;b++) acc2[a][b] = (f32x4){0.f,0.f,0.f,0.f};
  const unsigned short* w2e = w2b + (size_t)e*8*8*512;
#pragma unroll
  for (int ks2=0; ks2<8; ++ks2){
    bf16x8 af2[4], bf2v[2];
#pragma unroll
    for (int mt=0;mt<4;mt++)
      af2[mt] = *(const bf16x8*)(h1s + ((mw*4+mt)*8 + ks2)*512 + l*8);
#pragma unroll
    for (int ft=0;ft<2;ft++)
      bf2v[ft] = *(const bf16x8*)(w2e + (size_t)(ks2*8 + nw*2 + ft)*512 + l*8);
#pragma unroll
    for (int mt=0;mt<4;mt++)
#pragma unroll
      for (int ft=0;ft<2;ft++)
        acc2[mt][ft] = __builtin_amdgcn_mfma_f32_16x16x32_bf16(af2[mt], bf2v[ft], acc2[mt][ft], 0,0,0);
  }

  // GEMM3 in registers: h2 = relu(acc2 + b2), then dot with w3.
  // per lane: f0 = nw*32 + (l&15) (ft=0), f1 = f0+16 (ft=1)
  {
    const float* w3e = w3 + e*N2;
    const float* b2e = b2 + e*N2;
    const int f0 = nw*32 + (l&15);
    const int f1 = f0 + 16;
    float w3v0 = w3e[f0], w3v1 = w3e[f1];
    float b2v0 = b2e[f0], b2v1 = b2e[f1];
    float* red = (float*)As;   // [128][4]; As dead after GEMM1
#pragma unroll
    for (int mt=0;mt<4;mt++){
#pragma unroll
      for (int i=0;i<4;i++){
        float h20 = acc2[mt][0][i] + b2v0; h20 = h20 > 0.f ? h20 : 0.f;
        float h21 = acc2[mt][1][i] + b2v1; h21 = h21 > 0.f ? h21 : 0.f;
        float p = h20*w3v0 + h21*w3v1;
        p += __shfl_xor(p, 1);
        p += __shfl_xor(p, 2);
        p += __shfl_xor(p, 4);
        p += __shfl_xor(p, 8);
        if ((l & 15) == 0){
          int row = mw*64 + mt*16 + (l>>4)*4 + i;
          red[row*4 + nw] = p;
        }
      }
    }
    __syncthreads();
    if (tid < 128){
      int r = rl[tid];
      if (r >= 0){
        float sum = red[tid*4+0] + red[tid*4+1] + red[tid*4+2] + red[tid*4+3] + b3[e];
        eo[(size_t)r*E_N + e] = 1.f/(1.f + expf(-sum));
      }
    }
  }
}

// ---------------------------------------------------------------------------
// AG: final aggregation out[rt*B+row] = w0*eo[i0] + w1*eo[i1].
// ---------------------------------------------------------------------------
__global__ __launch_bounds__(512) void aggregate_kernel(
    const int* __restrict__ selIdx, const float2* __restrict__ selW,
    const float* __restrict__ eo, float* __restrict__ out)
{
  int row = blockIdx.x*512 + threadIdx.x;
#pragma unroll
  for (int rt=0; rt<2; rt++){
    int s = selIdx[rt*B_N + row];
    float2 wv = selW[rt*B_N + row];
    out[(size_t)rt*B_N + row] = wv.x * eo[(size_t)row*E_N + (s&7)]
                              + wv.y * eo[(size_t)row*E_N + ((s>>8)&7)];
  }
}

// ---------------------------------------------------------------------------
extern "C" void kernel_launch(void* const* d_in, const int* in_sizes, int n_in,
                              void* d_out, int out_size, void* d_ws, size_t ws_size,
                              hipStream_t stream){
  const float* text   = (const float*)d_in[0];
  const float* video  = (const float*)d_in[1];
  const float* exp_w1 = (const float*)d_in[2];
  const float* exp_b1 = (const float*)d_in[3];
  const float* exp_w2 = (const float*)d_in[4];
  const float* exp_b2 = (const float*)d_in[5];
  const float* exp_w3 = (const float*)d_in[6];
  const float* exp_b3 = (const float*)d_in[7];
  const float* tw1 = (const float*)d_in[8];
  const float* tb1 = (const float*)d_in[9];
  const float* tw2 = (const float*)d_in[10];
  const float* tb2 = (const float*)d_in[11];
  const float* vw1 = (const float*)d_in[12];
  const float* vb1 = (const float*)d_in[13];
  const float* vw2 = (const float*)d_in[14];
  const float* vb2 = (const float*)d_in[15];
  float* out = (float*)d_out;

  // ws layout (all offsets 16B-aligned)
  int*    counters = (int*)d_ws;                        // [0]=flag, [8..15]=cnt
  int*    flags    = counters + 16;                     // FLAG_CAP
  int*    selIdx   = flags + FLAG_CAP;                  // 2*B
  float2* selW     = (float2*)(selIdx + 2*B_N);         // 2*B
  int*    bucket   = (int*)(selW + 2*B_N);              // 8*B
  float*  eo       = (float*)(bucket + 8*B_N);          // B*8
  unsigned short* w1b  = (unsigned short*)(eo + (size_t)B_N*E_N);
  unsigned short* w2b  = w1b  + W1E;
  unsigned short* t_hi = w2b  + W2E;
  unsigned short* t_lo = t_hi + TRE;
  unsigned short* v_hi = t_lo + TRE;
  unsigned short* v_lo = v_hi + VRE;

  convert_weights<<<12544, 256, 0, stream>>>(exp_w1, exp_w2, tw1, vw1,
                                             w1b, w2b, t_hi, t_lo, v_hi, v_lo,
                                             counters);
  router_mfma<<<2048, 512, 0, stream>>>(text, video, t_hi, t_lo, v_hi, v_lo,
                                        tb1, tw2, tb2, vb1, vw2, vb2,
                                        selIdx, selW, flags, counters);
  router_exact<<<FLAG_CAP, 256, 0, stream>>>(text, video, tw1, tb1, tw2, tb2,
                                             vw1, vb1, vw2, vb2,
                                             selIdx, selW, flags, counters);
  bucket_build<<<256, 256, 0, stream>>>(selIdx, bucket, counters);
  expert_sparse<<<4096, 512, 0, stream>>>(text, video, w1b, exp_b1, w2b, exp_b2,
                                          exp_w3, exp_b3, bucket, counters, eo);
  aggregate_kernel<<<128, 512, 0, stream>>>(selIdx, selW, eo, out);
}